// Round 1
// baseline (578.112 us; speedup 1.0000x reference)
//
#include <hip/hip_runtime.h>
#include <hip/hip_bf16.h>
#include <cstdint>

// Problem constants
constexpr int BB = 64;    // batch
constexpr int TT = 12;    // time
constexpr int NN = 512;   // nodes
constexpr int FF = 64;    // features
constexpr int UU = 64;    // units
constexpr int MAXNZ = 128;

// ---------------------------------------------------------------------------
// Workspace layout (bytes):
//   floats:
//     lhs  (B,N,T)        : off 0,          393216 f
//     rhs  (B,N,T) [rhsS] : off 393216 f
//     beT  (N,N)          : off 786432 f
//     evals(B,N,MAXNZ)    : off 1048576 f,  4194304 f
//   ints (byte offsets):
//     nnz  : 20971520, 2048 B
//     cidx : 20973568, 262144 B
//     ccnt : 21235712, 2048 B
//     colj : 21237760, 262144 B
// ---------------------------------------------------------------------------
constexpr size_t OF_LHS   = 0;
constexpr size_t OF_RHS   = 393216;
constexpr size_t OF_BET   = 786432;
constexpr size_t OF_EVALS = 1048576;
constexpr size_t OB_NNZ   = 20971520;
constexpr size_t OB_CIDX  = 20973568;
constexpr size_t OB_CCNT  = 21235712;
constexpr size_t OB_COLJ  = 21237760;

__device__ __forceinline__ float wred_sum(float v) {
  #pragma unroll
  for (int off = 32; off; off >>= 1) v += __shfl_xor(v, off, 64);
  return v;
}

// ---------------------------------------------------------------------------
// Kernel 1: lhs[b,n,t] = sum_f (sum_t' x[b,t',n,f] W1[t']) * W2[f,t]
//           rhsS[b,n,t] = sum_f x[b,t,n,f] W3[f]   (rhs stored (B,N,T))
// wave per (b,n), lane = f
// ---------------------------------------------------------------------------
__global__ __launch_bounds__(256) void k_lhs_rhs(
    const float* __restrict__ x, const float* __restrict__ W1,
    const float* __restrict__ W2, const float* __restrict__ W3,
    float* __restrict__ lhs, float* __restrict__ rhsS)
{
  int unit = blockIdx.x * 4 + (threadIdx.x >> 6);   // b*512 + n
  int lane = threadIdx.x & 63;
  int b = unit >> 9, n = unit & 511;

  const float* xb = x + ((size_t)b * TT * NN + n) * FF + lane;
  float xv[12];
  #pragma unroll
  for (int t = 0; t < 12; ++t) xv[t] = xb[(size_t)t * NN * FF];

  float r1 = 0.f;
  #pragma unroll
  for (int t = 0; t < 12; ++t) r1 += xv[t] * W1[t];

  float w3 = W3[lane];

  float myl = 0.f, myr = 0.f;
  #pragma unroll
  for (int t = 0; t < 12; ++t) {
    float a = r1 * W2[lane * 12 + t];
    float c = xv[t] * w3;
    a = wred_sum(a);
    c = wred_sum(c);
    if (lane == t) { myl = a; myr = c; }
  }
  if (lane < 12) {
    lhs[(size_t)unit * 12 + lane]  = myl;
    rhsS[(size_t)unit * 12 + lane] = myr;
  }
}

// ---------------------------------------------------------------------------
// Kernel 2: beT[m,k] = be[k,m]
// ---------------------------------------------------------------------------
__global__ __launch_bounds__(256) void k_transpose(
    const float* __restrict__ be, float* __restrict__ beT)
{
  int i = blockIdx.x * 256 + threadIdx.x;  // 262144 total
  int k = i >> 9, m = i & 511;
  beT[m * 512 + k] = be[i];
}

// ---------------------------------------------------------------------------
// Kernel 3: row-wise compaction of mask A (deterministic, ordered by m)
// ---------------------------------------------------------------------------
__global__ void k_build_idx(const float* __restrict__ A,
                            int* __restrict__ nnz, int* __restrict__ cidx)
{
  int j = blockIdx.x;
  int lane = threadIdx.x;  // 64 threads
  unsigned long long lt = (1ull << lane) - 1ull;
  int base = 0;
  for (int c = 0; c < 8; ++c) {
    int m = c * 64 + lane;
    bool p = A[(size_t)j * 512 + m] > 0.5f;
    unsigned long long mask = __ballot(p);
    int pos = base + __popcll(mask & lt);
    if (p && pos < MAXNZ) cidx[j * MAXNZ + pos] = m;
    base += __popcll(mask);
  }
  if (lane == 0) nnz[j] = base > MAXNZ ? MAXNZ : base;
}

// ---------------------------------------------------------------------------
// Kernel 4: column lists: for each row-slot, append (j,slot) to column m's list
// (atomic order varies, but entries are pure scatters to unique evals slots)
// ---------------------------------------------------------------------------
__global__ void k_build_col(const int* __restrict__ nnz, const int* __restrict__ cidx,
                            int* __restrict__ ccnt, unsigned* __restrict__ colj)
{
  int j = blockIdx.x;
  int lane = threadIdx.x;
  int cnt = nnz[j];
  for (int s = lane; s < cnt; s += 64) {
    int m = cidx[j * MAXNZ + s];
    int pos = atomicAdd(&ccnt[m], 1);
    if (pos < MAXNZ) colj[m * MAXNZ + pos] = (unsigned)j | ((unsigned)s << 16);
  }
}

// ---------------------------------------------------------------------------
// Kernel 5: per (b, m-chunk of 4):
//   s[k] = sigmoid( sum_t lhs[b,k,t]*rhsS[b,m,t] + be[k,m] )     (in LDS)
//   for each (j,slot) in column m's list: evals[b,j,slot] = dot(Ve[j,:], s)
// ---------------------------------------------------------------------------
__global__ __launch_bounds__(256) void k_product_E(
    const float* __restrict__ lhs, const float* __restrict__ rhsS,
    const float* __restrict__ beT, const float* __restrict__ Ve,
    const int* __restrict__ ccnt, const unsigned* __restrict__ colj,
    float* __restrict__ evals)
{
  int b  = blockIdx.x;   // 0..63
  int mc = blockIdx.y;   // 0..127

  __shared__ float lhsL[512 * 13];  // stride 13: bank-conflict-free
  __shared__ float sL[512];
  __shared__ float rh[4 * 12];

  int tid = threadIdx.x;
  // stage lhs[b] (6144 floats) into LDS with stride-13 padding
  const float* src = lhs + (size_t)b * 512 * 12;
  for (int i = tid; i < 6144; i += 256) {
    int k = i / 12, t = i - k * 12;
    lhsL[k * 13 + t] = src[i];
  }
  if (tid < 48) rh[tid] = rhsS[((size_t)b * 512 + mc * 4) * 12 + tid];
  __syncthreads();

  int wave = tid >> 6, lane = tid & 63;

  for (int mm = 0; mm < 4; ++mm) {
    int m = mc * 4 + mm;
    __syncthreads();  // previous E-phase done reading sL
    for (int k = tid; k < 512; k += 256) {
      float p = beT[m * 512 + k];
      const float* lr = &lhsL[k * 13];
      #pragma unroll
      for (int t = 0; t < 12; ++t) p += lr[t] * rh[mm * 12 + t];
      sL[k] = 1.0f / (1.0f + __expf(-p));
    }
    __syncthreads();

    int cnt = ccnt[m];
    if (cnt > MAXNZ) cnt = MAXNZ;
    for (int e = wave; e < cnt; e += 4) {
      unsigned pk = colj[m * MAXNZ + e];
      int j = pk & 0xffff, slot = (int)(pk >> 16);
      const float* vr = Ve + (size_t)j * 512;
      float part = 0.f;
      #pragma unroll
      for (int kk = 0; kk < 8; ++kk) part += vr[kk * 64 + lane] * sL[kk * 64 + lane];
      part = wred_sum(part);
      if (lane == 0) evals[((size_t)b * 512 + j) * MAXNZ + slot] = part;
    }
  }
}

// ---------------------------------------------------------------------------
// Kernel 6: masked softmax over each (b,j) row's slots (in place in evals)
// ---------------------------------------------------------------------------
__global__ __launch_bounds__(256) void k_softmax(
    const int* __restrict__ nnz, float* __restrict__ evals)
{
  int unit = blockIdx.x * 4 + (threadIdx.x >> 6);  // b*512 + j
  int lane = threadIdx.x & 63;
  int j = unit & 511;
  int cnt = nnz[j];
  float* ev = evals + (size_t)unit * MAXNZ;
  float v0 = lane < cnt        ? ev[lane]      : -__builtin_inff();
  float v1 = (lane + 64) < cnt ? ev[lane + 64] : -__builtin_inff();
  float mx = fmaxf(v0, v1);
  #pragma unroll
  for (int off = 32; off; off >>= 1) mx = fmaxf(mx, __shfl_xor(mx, off, 64));
  float e0 = lane < cnt        ? __expf(v0 - mx) : 0.f;
  float e1 = (lane + 64) < cnt ? __expf(v1 - mx) : 0.f;
  float s = wred_sum(e0 + e1);
  float inv = 1.0f / s;
  if (lane < cnt)        ev[lane]      = e0 * inv;
  if ((lane + 64) < cnt) ev[lane + 64] = e1 * inv;
}

// ---------------------------------------------------------------------------
// Kernel 7: wave per (b,j):
//   conv[t,f] = sum_slot attn * x[b,t,idx,f]; out[b,t,j,u] = conv·K + bias
// ---------------------------------------------------------------------------
__global__ __launch_bounds__(256) void k_out(
    const float* __restrict__ x,
    const int* __restrict__ nnz, const int* __restrict__ cidx,
    const float* __restrict__ evals,
    const float* __restrict__ K, const float* __restrict__ bias,
    float* __restrict__ out)
{
  int wv = threadIdx.x >> 6, lane = threadIdx.x & 63;
  int unit = blockIdx.x * 4 + wv;  // b*512 + j
  int b = unit >> 9, j = unit & 511;

  __shared__ float convL[4][64];
  __shared__ float valL[4][MAXNZ];
  __shared__ int   idxL[4][MAXNZ];

  int cnt = nnz[j];
  for (int s = lane; s < cnt; s += 64) {
    idxL[wv][s] = cidx[j * MAXNZ + s];
    valL[wv][s] = evals[(size_t)unit * MAXNZ + s];
  }

  // preload K column for this lane's u
  float kc[64];
  #pragma unroll
  for (int f = 0; f < 64; ++f) kc[f] = K[f * 64 + lane];
  float bs = bias[lane];
  __syncthreads();

  for (int t = 0; t < 12; ++t) {
    const float* xt = x + ((size_t)(b * 12 + t)) * 512 * 64;
    float acc = 0.f;
    for (int s = 0; s < cnt; ++s)
      acc += valL[wv][s] * xt[(size_t)idxL[wv][s] * 64 + lane];
    convL[wv][lane] = acc;
    __syncthreads();
    float o = bs;
    const float4* cv = (const float4*)convL[wv];
    #pragma unroll
    for (int i = 0; i < 16; ++i) {
      float4 c4 = cv[i];
      o += c4.x * kc[4*i] + c4.y * kc[4*i+1] + c4.z * kc[4*i+2] + c4.w * kc[4*i+3];
    }
    out[((size_t)(b * 12 + t) * 512 + j) * 64 + lane] = o;
    __syncthreads();
  }
}

// ---------------------------------------------------------------------------
extern "C" void kernel_launch(void* const* d_in, const int* in_sizes, int n_in,
                              void* d_out, int out_size, void* d_ws, size_t ws_size,
                              hipStream_t stream)
{
  const float* x    = (const float*)d_in[0];  // (B,T,N,F)
  const float* A    = (const float*)d_in[1];  // (N,N)
  const float* W1   = (const float*)d_in[2];  // (T,1)
  const float* W2   = (const float*)d_in[3];  // (F,T)
  const float* W3   = (const float*)d_in[4];  // (F,1)
  const float* Ve   = (const float*)d_in[5];  // (N,N)
  const float* be   = (const float*)d_in[6];  // (N,N)
  const float* K    = (const float*)d_in[7];  // (F,U)
  const float* bias = (const float*)d_in[8];  // (U,)
  float* out = (float*)d_out;

  char* ws = (char*)d_ws;
  float* lhs   = (float*)ws + OF_LHS;
  float* rhsS  = (float*)ws + OF_RHS;
  float* beT   = (float*)ws + OF_BET;
  float* evals = (float*)ws + OF_EVALS;
  int*      nnz  = (int*)(ws + OB_NNZ);
  int*      cidx = (int*)(ws + OB_CIDX);
  int*      ccnt = (int*)(ws + OB_CCNT);
  unsigned* colj = (unsigned*)(ws + OB_COLJ);

  // zero column counters each launch (deterministic work)
  hipMemsetAsync(ccnt, 0, NN * sizeof(int), stream);

  // 1. lhs / rhs
  k_lhs_rhs<<<dim3(BB * NN / 4), dim3(256), 0, stream>>>(x, W1, W2, W3, lhs, rhsS);
  // 2. transpose be
  k_transpose<<<dim3(NN * NN / 256), dim3(256), 0, stream>>>(be, beT);
  // 3. row index lists
  k_build_idx<<<dim3(NN), dim3(64), 0, stream>>>(A, nnz, cidx);
  // 4. column lists
  k_build_col<<<dim3(NN), dim3(64), 0, stream>>>(nnz, cidx, ccnt, colj);
  // 5. product + sigmoid + masked E
  k_product_E<<<dim3(BB, NN / 4), dim3(256), 0, stream>>>(lhs, rhsS, beT, Ve, ccnt, colj, evals);
  // 6. softmax over slots
  k_softmax<<<dim3(BB * NN / 4), dim3(256), 0, stream>>>(nnz, evals);
  // 7. sparse conv + output GEMM
  k_out<<<dim3(BB * NN / 4), dim3(256), 0, stream>>>(x, nnz, cidx, evals, K, bias, out);
}

// Round 3
// 357.927 us; speedup vs baseline: 1.6152x; 1.6152x over previous
//
#include <hip/hip_runtime.h>
#include <hip/hip_bf16.h>
#include <cstdint>

// Problem constants
constexpr int BB = 64;    // batch
constexpr int TT = 12;    // time
constexpr int NN = 512;   // nodes
constexpr int FF = 64;    // features
constexpr int UU = 64;    // units
constexpr int MAXNZ = 128;

// ---------------------------------------------------------------------------
// Workspace layout (bytes):
//   floats:
//     lhs  (B,N,T)        : off 0,          393216 f
//     rhs  (B,N,T) [rhsS] : off 393216 f
//     beT  (N,N)          : off 786432 f
//     evals(B,N,MAXNZ)    : off 1048576 f,  4194304 f
//   ints (byte offsets):
//     nnz  : 20971520, 2048 B
//     cidx : 20973568, 262144 B
//     ccnt : 21235712, 2048 B
//     colj : 21237760, 262144 B
// ---------------------------------------------------------------------------
constexpr size_t OF_LHS   = 0;
constexpr size_t OF_RHS   = 393216;
constexpr size_t OF_BET   = 786432;
constexpr size_t OF_EVALS = 1048576;
constexpr size_t OB_NNZ   = 20971520;
constexpr size_t OB_CIDX  = 20973568;
constexpr size_t OB_CCNT  = 21235712;
constexpr size_t OB_COLJ  = 21237760;

__device__ __forceinline__ float wred_sum(float v) {
  #pragma unroll
  for (int off = 32; off; off >>= 1) v += __shfl_xor(v, off, 64);
  return v;
}

// ---------------------------------------------------------------------------
// Kernel 1: lhs[b,n,t] = sum_f (sum_t' x[b,t',n,f] W1[t']) * W2[f,t]
//           rhsS[b,n,t] = sum_f x[b,t,n,f] W3[f]   (rhs stored (B,N,T))
// wave per (b,n), lane = f
// ---------------------------------------------------------------------------
__global__ __launch_bounds__(256) void k_lhs_rhs(
    const float* __restrict__ x, const float* __restrict__ W1,
    const float* __restrict__ W2, const float* __restrict__ W3,
    float* __restrict__ lhs, float* __restrict__ rhsS)
{
  int unit = blockIdx.x * 4 + (threadIdx.x >> 6);   // b*512 + n
  int lane = threadIdx.x & 63;
  int b = unit >> 9, n = unit & 511;

  const float* xb = x + ((size_t)b * TT * NN + n) * FF + lane;
  float xv[12];
  #pragma unroll
  for (int t = 0; t < 12; ++t) xv[t] = xb[(size_t)t * NN * FF];

  float r1 = 0.f;
  #pragma unroll
  for (int t = 0; t < 12; ++t) r1 += xv[t] * W1[t];

  float w3 = W3[lane];

  float myl = 0.f, myr = 0.f;
  #pragma unroll
  for (int t = 0; t < 12; ++t) {
    float a = r1 * W2[lane * 12 + t];
    float c = xv[t] * w3;
    a = wred_sum(a);
    c = wred_sum(c);
    if (lane == t) { myl = a; myr = c; }
  }
  if (lane < 12) {
    lhs[(size_t)unit * 12 + lane]  = myl;
    rhsS[(size_t)unit * 12 + lane] = myr;
  }
}

// ---------------------------------------------------------------------------
// Kernel 2: beT[m,k] = be[k,m]
// ---------------------------------------------------------------------------
__global__ __launch_bounds__(256) void k_transpose(
    const float* __restrict__ be, float* __restrict__ beT)
{
  int i = blockIdx.x * 256 + threadIdx.x;  // 262144 total
  int k = i >> 9, m = i & 511;
  beT[m * 512 + k] = be[i];
}

// ---------------------------------------------------------------------------
// Kernel 3: row-wise compaction of mask A (deterministic, ordered by m)
// ---------------------------------------------------------------------------
__global__ void k_build_idx(const float* __restrict__ A,
                            int* __restrict__ nnz, int* __restrict__ cidx)
{
  int j = blockIdx.x;
  int lane = threadIdx.x;  // 64 threads
  unsigned long long lt = (1ull << lane) - 1ull;
  int base = 0;
  for (int c = 0; c < 8; ++c) {
    int m = c * 64 + lane;
    bool p = A[(size_t)j * 512 + m] > 0.5f;
    unsigned long long mask = __ballot(p);
    int pos = base + __popcll(mask & lt);
    if (p && pos < MAXNZ) cidx[j * MAXNZ + pos] = m;
    base += __popcll(mask);
  }
  if (lane == 0) nnz[j] = base > MAXNZ ? MAXNZ : base;
}

// ---------------------------------------------------------------------------
// Kernel 4: column lists: for each row-slot, append (j,slot) to column m's list
// (atomic order varies, but entries are pure scatters to unique evals slots)
// ---------------------------------------------------------------------------
__global__ void k_build_col(const int* __restrict__ nnz, const int* __restrict__ cidx,
                            int* __restrict__ ccnt, unsigned* __restrict__ colj)
{
  int j = blockIdx.x;
  int lane = threadIdx.x;
  int cnt = nnz[j];
  for (int s = lane; s < cnt; s += 64) {
    int m = cidx[j * MAXNZ + s];
    int pos = atomicAdd(&ccnt[m], 1);
    if (pos < MAXNZ) colj[m * MAXNZ + pos] = (unsigned)j | ((unsigned)s << 16);
  }
}

// ---------------------------------------------------------------------------
// Kernel 5: per (b, m-chunk of 4):
//   s[k] = sigmoid( sum_t lhs[b,k,t]*rhsS[b,m,t] + be[k,m] )     (in LDS)
//   for each (j,slot) in column m's list: evals[b,j,slot] = dot(Ve[j,:], s)
// ---------------------------------------------------------------------------
__global__ __launch_bounds__(256) void k_product_E(
    const float* __restrict__ lhs, const float* __restrict__ rhsS,
    const float* __restrict__ beT, const float* __restrict__ Ve,
    const int* __restrict__ ccnt, const unsigned* __restrict__ colj,
    float* __restrict__ evals)
{
  int b  = blockIdx.x;   // 0..63
  int mc = blockIdx.y;   // 0..127

  __shared__ float lhsL[512 * 13];  // stride 13: bank-conflict-free
  __shared__ float sL[512];
  __shared__ float rh[4 * 12];

  int tid = threadIdx.x;
  // stage lhs[b] (6144 floats) into LDS with stride-13 padding
  const float* src = lhs + (size_t)b * 512 * 12;
  for (int i = tid; i < 6144; i += 256) {
    int k = i / 12, t = i - k * 12;
    lhsL[k * 13 + t] = src[i];
  }
  if (tid < 48) rh[tid] = rhsS[((size_t)b * 512 + mc * 4) * 12 + tid];
  __syncthreads();

  int wave = tid >> 6, lane = tid & 63;

  for (int mm = 0; mm < 4; ++mm) {
    int m = mc * 4 + mm;
    __syncthreads();  // previous E-phase done reading sL
    for (int k = tid; k < 512; k += 256) {
      float p = beT[m * 512 + k];
      const float* lr = &lhsL[k * 13];
      #pragma unroll
      for (int t = 0; t < 12; ++t) p += lr[t] * rh[mm * 12 + t];
      sL[k] = 1.0f / (1.0f + __expf(-p));
    }
    __syncthreads();

    int cnt = ccnt[m];
    if (cnt > MAXNZ) cnt = MAXNZ;
    for (int e = wave; e < cnt; e += 4) {
      unsigned pk = colj[m * MAXNZ + e];
      int j = pk & 0xffff, slot = (int)(pk >> 16);
      const float* vr = Ve + (size_t)j * 512;
      float part = 0.f;
      #pragma unroll
      for (int kk = 0; kk < 8; ++kk) part += vr[kk * 64 + lane] * sL[kk * 64 + lane];
      part = wred_sum(part);
      if (lane == 0) evals[((size_t)b * 512 + j) * MAXNZ + slot] = part;
    }
  }
}

// ---------------------------------------------------------------------------
// Kernel 6: masked softmax over each (b,j) row's slots (in place in evals)
// ---------------------------------------------------------------------------
__global__ __launch_bounds__(256) void k_softmax(
    const int* __restrict__ nnz, float* __restrict__ evals)
{
  int unit = blockIdx.x * 4 + (threadIdx.x >> 6);  // b*512 + j
  int lane = threadIdx.x & 63;
  int j = unit & 511;
  int cnt = nnz[j];
  float* ev = evals + (size_t)unit * MAXNZ;
  float v0 = lane < cnt        ? ev[lane]      : -__builtin_inff();
  float v1 = (lane + 64) < cnt ? ev[lane + 64] : -__builtin_inff();
  float mx = fmaxf(v0, v1);
  #pragma unroll
  for (int off = 32; off; off >>= 1) mx = fmaxf(mx, __shfl_xor(mx, off, 64));
  float e0 = lane < cnt        ? __expf(v0 - mx) : 0.f;
  float e1 = (lane + 64) < cnt ? __expf(v1 - mx) : 0.f;
  float s = wred_sum(e0 + e1);
  float inv = 1.0f / s;
  if (lane < cnt)        ev[lane]      = e0 * inv;
  if ((lane + 64) < cnt) ev[lane + 64] = e1 * inv;
}

// ---------------------------------------------------------------------------
// Kernel 7 (v3): wave per (b,j).
//   Phase A: acc[t] += attn[s] * x[b,t,idx[s],lane]  -- 12 independent loads
//            per neighbor s => 12-way MLP.
//   Phase B: out[b,t,j,u] = conv[t,:]·K[:,u] + bias[u], conv staged in LDS.
// XCD swizzle (FIXED): grid = 8192 blocks (4 units each). 8192 % 8 == 0, so
//   sbid = (bid&7)*1024 + (bid>>3) is bijective; XCD i owns 1024 consecutive
//   sbids = 8 consecutive b's; instantaneous window ~1 b = 1.5 MB < 4 MB L2.
// ---------------------------------------------------------------------------
__global__ __launch_bounds__(256) void k_out3(
    const float* __restrict__ x,
    const int* __restrict__ nnz, const int* __restrict__ cidx,
    const float* __restrict__ evals,
    const float* __restrict__ K, const float* __restrict__ bias,
    float* __restrict__ out)
{
  int wv = threadIdx.x >> 6, lane = threadIdx.x & 63;
  int bid = blockIdx.x;
  int sbid = (bid & 7) * 1024 + (bid >> 3);  // bijective on [0,8192)
  int unit = sbid * 4 + wv;                  // b*512 + j
  int b = unit >> 9, j = unit & 511;

  __shared__ float convL[4][12][64];
  __shared__ float valL[4][MAXNZ];
  __shared__ int   idxL[4][MAXNZ];

  int cnt = nnz[j];
  for (int s = lane; s < cnt; s += 64) {
    idxL[wv][s] = cidx[j * MAXNZ + s];
    valL[wv][s] = evals[(size_t)unit * MAXNZ + s];
  }
  // wave-private LDS: same-wave ds ops are ordered; no barrier needed here

  float acc[12];
  #pragma unroll
  for (int t = 0; t < 12; ++t) acc[t] = 0.f;

  const float* xb = x + (size_t)b * TT * NN * FF + lane;
  for (int s = 0; s < cnt; ++s) {
    float v = valL[wv][s];
    const float* xk = xb + (size_t)idxL[wv][s] * FF;
    #pragma unroll
    for (int t = 0; t < 12; ++t)
      acc[t] = fmaf(v, xk[(size_t)t * NN * FF], acc[t]);
  }
  #pragma unroll
  for (int t = 0; t < 12; ++t) convL[wv][t][lane] = acc[t];

  float kc[64];
  #pragma unroll
  for (int f = 0; f < 64; ++f) kc[f] = K[f * 64 + lane];
  float bs = bias[lane];
  __syncthreads();  // conv tile visible (also orders same-wave cross-lane reads)

  #pragma unroll
  for (int t = 0; t < 12; ++t) {
    const float4* cv = (const float4*)convL[wv][t];
    float o = bs;
    #pragma unroll
    for (int i = 0; i < 16; ++i) {
      float4 c4 = cv[i];
      o += c4.x * kc[4*i] + c4.y * kc[4*i+1] + c4.z * kc[4*i+2] + c4.w * kc[4*i+3];
    }
    out[((size_t)(b * TT + t) * NN + j) * UU + lane] = o;
  }
}

// ---------------------------------------------------------------------------
extern "C" void kernel_launch(void* const* d_in, const int* in_sizes, int n_in,
                              void* d_out, int out_size, void* d_ws, size_t ws_size,
                              hipStream_t stream)
{
  const float* x    = (const float*)d_in[0];  // (B,T,N,F)
  const float* A    = (const float*)d_in[1];  // (N,N)
  const float* W1   = (const float*)d_in[2];  // (T,1)
  const float* W2   = (const float*)d_in[3];  // (F,T)
  const float* W3   = (const float*)d_in[4];  // (F,1)
  const float* Ve   = (const float*)d_in[5];  // (N,N)
  const float* be   = (const float*)d_in[6];  // (N,N)
  const float* K    = (const float*)d_in[7];  // (F,U)
  const float* bias = (const float*)d_in[8];  // (U,)
  float* out = (float*)d_out;

  char* ws = (char*)d_ws;
  float* lhs   = (float*)ws + OF_LHS;
  float* rhsS  = (float*)ws + OF_RHS;
  float* beT   = (float*)ws + OF_BET;
  float* evals = (float*)ws + OF_EVALS;
  int*      nnz  = (int*)(ws + OB_NNZ);
  int*      cidx = (int*)(ws + OB_CIDX);
  int*      ccnt = (int*)(ws + OB_CCNT);
  unsigned* colj = (unsigned*)(ws + OB_COLJ);

  // zero column counters each launch (deterministic work)
  hipMemsetAsync(ccnt, 0, NN * sizeof(int), stream);

  // 1. lhs / rhs
  k_lhs_rhs<<<dim3(BB * NN / 4), dim3(256), 0, stream>>>(x, W1, W2, W3, lhs, rhsS);
  // 2. transpose be
  k_transpose<<<dim3(NN * NN / 256), dim3(256), 0, stream>>>(be, beT);
  // 3. row index lists
  k_build_idx<<<dim3(NN), dim3(64), 0, stream>>>(A, nnz, cidx);
  // 4. column lists
  k_build_col<<<dim3(NN), dim3(64), 0, stream>>>(nnz, cidx, ccnt, colj);
  // 5. product + sigmoid + masked E
  k_product_E<<<dim3(BB, NN / 4), dim3(256), 0, stream>>>(lhs, rhsS, beT, Ve, ccnt, colj, evals);
  // 6. softmax over slots
  k_softmax<<<dim3(BB * NN / 4), dim3(256), 0, stream>>>(nnz, evals);
  // 7. sparse conv + output GEMM (t-batched, XCD-swizzled)
  k_out3<<<dim3(BB * NN / 4), dim3(256), 0, stream>>>(x, nnz, cidx, evals, K, bias, out);
}

// Round 4
// 302.310 us; speedup vs baseline: 1.9123x; 1.1840x over previous
//
#include <hip/hip_runtime.h>
#include <hip/hip_bf16.h>
#include <cstdint>

// Problem constants
constexpr int BB = 64;    // batch
constexpr int TT = 12;    // time
constexpr int NN = 512;   // nodes
constexpr int FF = 64;    // features
constexpr int UU = 64;    // units
constexpr int MAXNZ = 128;
constexpr int MCH = 16;   // m-columns per k_product_E block

// ---------------------------------------------------------------------------
// Workspace layout (bytes):
//   floats:
//     lhs  (B,N,T)        : off 0,          393216 f
//     rhs  (B,N,T) [rhsS] : off 393216 f
//     beT  (N,N)          : off 786432 f
//     evals(B,N,MAXNZ)    : off 1048576 f,  4194304 f
//   ints (byte offsets):
//     nnz  : 20971520, 2048 B
//     cidx : 20973568, 262144 B
//     ccnt : 21235712, 2048 B
//     colj : 21237760, 262144 B
// ---------------------------------------------------------------------------
constexpr size_t OF_LHS   = 0;
constexpr size_t OF_RHS   = 393216;
constexpr size_t OF_BET   = 786432;
constexpr size_t OF_EVALS = 1048576;
constexpr size_t OB_NNZ   = 20971520;
constexpr size_t OB_CIDX  = 20973568;
constexpr size_t OB_CCNT  = 21235712;
constexpr size_t OB_COLJ  = 21237760;

__device__ __forceinline__ float wred_sum(float v) {
  #pragma unroll
  for (int off = 32; off; off >>= 1) v += __shfl_xor(v, off, 64);
  return v;
}

// ---------------------------------------------------------------------------
// Kernel 1: lhs[b,n,t] = sum_f (sum_t' x[b,t',n,f] W1[t']) * W2[f,t]
//           rhsS[b,n,t] = sum_f x[b,t,n,f] W3[f]   (rhs stored (B,N,T))
// wave per (b,n), lane = f
// ---------------------------------------------------------------------------
__global__ __launch_bounds__(256) void k_lhs_rhs(
    const float* __restrict__ x, const float* __restrict__ W1,
    const float* __restrict__ W2, const float* __restrict__ W3,
    float* __restrict__ lhs, float* __restrict__ rhsS)
{
  int unit = blockIdx.x * 4 + (threadIdx.x >> 6);   // b*512 + n
  int lane = threadIdx.x & 63;
  int b = unit >> 9, n = unit & 511;

  const float* xb = x + ((size_t)b * TT * NN + n) * FF + lane;
  float xv[12];
  #pragma unroll
  for (int t = 0; t < 12; ++t) xv[t] = xb[(size_t)t * NN * FF];

  float r1 = 0.f;
  #pragma unroll
  for (int t = 0; t < 12; ++t) r1 += xv[t] * W1[t];

  float w3 = W3[lane];

  float myl = 0.f, myr = 0.f;
  #pragma unroll
  for (int t = 0; t < 12; ++t) {
    float a = r1 * W2[lane * 12 + t];
    float c = xv[t] * w3;
    a = wred_sum(a);
    c = wred_sum(c);
    if (lane == t) { myl = a; myr = c; }
  }
  if (lane < 12) {
    lhs[(size_t)unit * 12 + lane]  = myl;
    rhsS[(size_t)unit * 12 + lane] = myr;
  }
}

// ---------------------------------------------------------------------------
// Kernel 2: beT[m,k] = be[k,m]
// ---------------------------------------------------------------------------
__global__ __launch_bounds__(256) void k_transpose(
    const float* __restrict__ be, float* __restrict__ beT)
{
  int i = blockIdx.x * 256 + threadIdx.x;  // 262144 total
  int k = i >> 9, m = i & 511;
  beT[m * 512 + k] = be[i];
}

// ---------------------------------------------------------------------------
// Kernel 3: row-wise compaction of mask A (deterministic, ordered by m)
// ---------------------------------------------------------------------------
__global__ void k_build_idx(const float* __restrict__ A,
                            int* __restrict__ nnz, int* __restrict__ cidx)
{
  int j = blockIdx.x;
  int lane = threadIdx.x;  // 64 threads
  unsigned long long lt = (1ull << lane) - 1ull;
  int base = 0;
  for (int c = 0; c < 8; ++c) {
    int m = c * 64 + lane;
    bool p = A[(size_t)j * 512 + m] > 0.5f;
    unsigned long long mask = __ballot(p);
    int pos = base + __popcll(mask & lt);
    if (p && pos < MAXNZ) cidx[j * MAXNZ + pos] = m;
    base += __popcll(mask);
  }
  if (lane == 0) nnz[j] = base > MAXNZ ? MAXNZ : base;
}

// ---------------------------------------------------------------------------
// Kernel 4: column lists: for each row-slot, append (j,slot) to column m's list
// (atomic order varies, but entries are pure scatters to unique evals slots)
// ---------------------------------------------------------------------------
__global__ void k_build_col(const int* __restrict__ nnz, const int* __restrict__ cidx,
                            int* __restrict__ ccnt, unsigned* __restrict__ colj)
{
  int j = blockIdx.x;
  int lane = threadIdx.x;
  int cnt = nnz[j];
  for (int s = lane; s < cnt; s += 64) {
    int m = cidx[j * MAXNZ + s];
    int pos = atomicAdd(&ccnt[m], 1);
    if (pos < MAXNZ) colj[m * MAXNZ + pos] = (unsigned)j | ((unsigned)s << 16);
  }
}

// ---------------------------------------------------------------------------
// Kernel 5 (v2): block = (b, chunk of MCH=16 m's), 256 threads.
//   Repeat 4x: sigmoid phase fills sL[4][512] (4 columns), then wave w walks
//   column w's entry list; each 16-lane group dots one entry:
//   32 FMA/lane + 4-step shuffle reduce (was 8 FMA + 6-step 64-lane reduce).
//   sL reads broadcast across the 4 groups (conflict-free); Ve reads are
//   64B-contiguous per group (Ve = 1 MB, L2-resident).
// ---------------------------------------------------------------------------
__global__ __launch_bounds__(256) void k_product_E(
    const float* __restrict__ lhs, const float* __restrict__ rhsS,
    const float* __restrict__ beT, const float* __restrict__ Ve,
    const int* __restrict__ ccnt, const unsigned* __restrict__ colj,
    float* __restrict__ evals)
{
  int b  = blockIdx.x;   // 0..63
  int mc = blockIdx.y;   // 0..31

  __shared__ float lhsL[512 * 13];  // stride 13: conflict-free
  __shared__ float sL[4][512];
  __shared__ float rh[MCH * 12];

  int tid = threadIdx.x;
  const float* src = lhs + (size_t)b * 512 * 12;
  for (int i = tid; i < 6144; i += 256) {
    int k = i / 12, t = i - k * 12;
    lhsL[k * 13 + t] = src[i];
  }
  if (tid < MCH * 12) rh[tid] = rhsS[((size_t)b * 512 + mc * MCH) * 12 + tid];
  __syncthreads();

  int wave = tid >> 6, lane = tid & 63;
  int grp = lane >> 4, lg = lane & 15;

  for (int g = 0; g < MCH / 4; ++g) {
    if (g) __syncthreads();  // previous E-phase done reading sL
    // sigmoid for columns m = mc*MCH + g*4 + w, w=0..3
    for (int i = tid; i < 4 * 512; i += 256) {
      int w = i >> 9, k = i & 511;
      int m = mc * MCH + g * 4 + w;
      float p = beT[m * 512 + k];
      const float* lr = &lhsL[k * 13];
      const float* rw = &rh[(g * 4 + w) * 12];
      #pragma unroll
      for (int t = 0; t < 12; ++t) p += lr[t] * rw[t];
      sL[w][k] = 1.0f / (1.0f + __expf(-p));
    }
    __syncthreads();

    // wave w owns column m = mc*MCH + g*4 + w
    int m = mc * MCH + g * 4 + wave;
    int cnt = ccnt[m];
    if (cnt > MAXNZ) cnt = MAXNZ;
    const float* sw = sL[wave];
    for (int e = grp; e < cnt; e += 4) {
      unsigned pk = colj[m * MAXNZ + e];
      int j = pk & 0xffff, slot = (int)(pk >> 16);
      const float* vr = Ve + (size_t)j * 512;
      float part = 0.f;
      #pragma unroll
      for (int kk = 0; kk < 32; ++kk)
        part = fmaf(vr[kk * 16 + lg], sw[kk * 16 + lg], part);
      #pragma unroll
      for (int off = 8; off; off >>= 1) part += __shfl_xor(part, off, 64);
      if (lg == 0) evals[((size_t)b * 512 + j) * MAXNZ + slot] = part;
    }
  }
}

// ---------------------------------------------------------------------------
// Kernel 6: masked softmax over each (b,j) row's slots (in place in evals)
// ---------------------------------------------------------------------------
__global__ __launch_bounds__(256) void k_softmax(
    const int* __restrict__ nnz, float* __restrict__ evals)
{
  int unit = blockIdx.x * 4 + (threadIdx.x >> 6);  // b*512 + j
  int lane = threadIdx.x & 63;
  int j = unit & 511;
  int cnt = nnz[j];
  float* ev = evals + (size_t)unit * MAXNZ;
  float v0 = lane < cnt        ? ev[lane]      : -__builtin_inff();
  float v1 = (lane + 64) < cnt ? ev[lane + 64] : -__builtin_inff();
  float mx = fmaxf(v0, v1);
  #pragma unroll
  for (int off = 32; off; off >>= 1) mx = fmaxf(mx, __shfl_xor(mx, off, 64));
  float e0 = lane < cnt        ? __expf(v0 - mx) : 0.f;
  float e1 = (lane + 64) < cnt ? __expf(v1 - mx) : 0.f;
  float s = wred_sum(e0 + e1);
  float inv = 1.0f / s;
  if (lane < cnt)        ev[lane]      = e0 * inv;
  if ((lane + 64) < cnt) ev[lane + 64] = e1 * inv;
}

// ---------------------------------------------------------------------------
// Kernel 7 (v3): wave per (b,j).
//   Phase A: acc[t] += attn[s] * x[b,t,idx[s],lane]  -- 12 independent loads
//            per neighbor s => 12-way MLP.
//   Phase B: out[b,t,j,u] = conv[t,:]·K[:,u] + bias[u], conv staged in LDS.
// XCD swizzle: grid = 8192, sbid = (bid&7)*1024 + (bid>>3) bijective;
// XCD i owns 8 consecutive b's; window ~1 b = 1.5 MB < 4 MB L2.
// ---------------------------------------------------------------------------
__global__ __launch_bounds__(256) void k_out3(
    const float* __restrict__ x,
    const int* __restrict__ nnz, const int* __restrict__ cidx,
    const float* __restrict__ evals,
    const float* __restrict__ K, const float* __restrict__ bias,
    float* __restrict__ out)
{
  int wv = threadIdx.x >> 6, lane = threadIdx.x & 63;
  int bid = blockIdx.x;
  int sbid = (bid & 7) * 1024 + (bid >> 3);  // bijective on [0,8192)
  int unit = sbid * 4 + wv;                  // b*512 + j
  int b = unit >> 9, j = unit & 511;

  __shared__ float convL[4][12][64];
  __shared__ float valL[4][MAXNZ];
  __shared__ int   idxL[4][MAXNZ];

  int cnt = nnz[j];
  for (int s = lane; s < cnt; s += 64) {
    idxL[wv][s] = cidx[j * MAXNZ + s];
    valL[wv][s] = evals[(size_t)unit * MAXNZ + s];
  }
  // wave-private LDS: same-wave ds ops are ordered; no barrier needed here

  float acc[12];
  #pragma unroll
  for (int t = 0; t < 12; ++t) acc[t] = 0.f;

  const float* xb = x + (size_t)b * TT * NN * FF + lane;
  for (int s = 0; s < cnt; ++s) {
    float v = valL[wv][s];
    const float* xk = xb + (size_t)idxL[wv][s] * FF;
    #pragma unroll
    for (int t = 0; t < 12; ++t)
      acc[t] = fmaf(v, xk[(size_t)t * NN * FF], acc[t]);
  }
  #pragma unroll
  for (int t = 0; t < 12; ++t) convL[wv][t][lane] = acc[t];

  float kc[64];
  #pragma unroll
  for (int f = 0; f < 64; ++f) kc[f] = K[f * 64 + lane];
  float bs = bias[lane];
  __syncthreads();  // conv tile visible (also orders same-wave cross-lane reads)

  #pragma unroll
  for (int t = 0; t < 12; ++t) {
    const float4* cv = (const float4*)convL[wv][t];
    float o = bs;
    #pragma unroll
    for (int i = 0; i < 16; ++i) {
      float4 c4 = cv[i];
      o += c4.x * kc[4*i] + c4.y * kc[4*i+1] + c4.z * kc[4*i+2] + c4.w * kc[4*i+3];
    }
    out[((size_t)(b * TT + t) * NN + j) * UU + lane] = o;
  }
}

// ---------------------------------------------------------------------------
extern "C" void kernel_launch(void* const* d_in, const int* in_sizes, int n_in,
                              void* d_out, int out_size, void* d_ws, size_t ws_size,
                              hipStream_t stream)
{
  const float* x    = (const float*)d_in[0];  // (B,T,N,F)
  const float* A    = (const float*)d_in[1];  // (N,N)
  const float* W1   = (const float*)d_in[2];  // (T,1)
  const float* W2   = (const float*)d_in[3];  // (F,T)
  const float* W3   = (const float*)d_in[4];  // (F,1)
  const float* Ve   = (const float*)d_in[5];  // (N,N)
  const float* be   = (const float*)d_in[6];  // (N,N)
  const float* K    = (const float*)d_in[7];  // (F,U)
  const float* bias = (const float*)d_in[8];  // (U,)
  float* out = (float*)d_out;

  char* ws = (char*)d_ws;
  float* lhs   = (float*)ws + OF_LHS;
  float* rhsS  = (float*)ws + OF_RHS;
  float* beT   = (float*)ws + OF_BET;
  float* evals = (float*)ws + OF_EVALS;
  int*      nnz  = (int*)(ws + OB_NNZ);
  int*      cidx = (int*)(ws + OB_CIDX);
  int*      ccnt = (int*)(ws + OB_CCNT);
  unsigned* colj = (unsigned*)(ws + OB_COLJ);

  // zero column counters each launch (deterministic work)
  hipMemsetAsync(ccnt, 0, NN * sizeof(int), stream);

  // 1. lhs / rhs
  k_lhs_rhs<<<dim3(BB * NN / 4), dim3(256), 0, stream>>>(x, W1, W2, W3, lhs, rhsS);
  // 2. transpose be
  k_transpose<<<dim3(NN * NN / 256), dim3(256), 0, stream>>>(be, beT);
  // 3. row index lists
  k_build_idx<<<dim3(NN), dim3(64), 0, stream>>>(A, nnz, cidx);
  // 4. column lists
  k_build_col<<<dim3(NN), dim3(64), 0, stream>>>(nnz, cidx, ccnt, colj);
  // 5. product + sigmoid + masked E (16 columns/block, 16-lane entry groups)
  k_product_E<<<dim3(BB, NN / MCH), dim3(256), 0, stream>>>(lhs, rhsS, beT, Ve, ccnt, colj, evals);
  // 6. softmax over slots
  k_softmax<<<dim3(BB * NN / 4), dim3(256), 0, stream>>>(nnz, evals);
  // 7. sparse conv + output GEMM (t-batched, XCD-swizzled)
  k_out3<<<dim3(BB * NN / 4), dim3(256), 0, stream>>>(x, nnz, cidx, evals, K, bias, out);
}